// Round 12
// baseline (1352.153 us; speedup 1.0000x reference)
//
#include <hip/hip_runtime.h>
#include <hip/hip_bf16.h>
#include <stdint.h>

typedef __bf16 bf16x8 __attribute__((ext_vector_type(8)));
typedef __bf16 bf16x4 __attribute__((ext_vector_type(4)));
typedef float  f32x4  __attribute__((ext_vector_type(4)));

#define DIN   128
#define KA    384
#define HD    512
#define NB    1152
#define DOUTD 128
#define NOBJ  50000
#define NTRI  200000
#define NSCAN 98
#define SB_STRIDE 520
#define CH    50000   // triples per chunk (hbuf = 51.2MB fits xbuf slot)

// ---- async 16B global->LDS DMA ----
__device__ __forceinline__ void gload16(const void* g, void* l) {
    __builtin_amdgcn_global_load_lds(
        (const __attribute__((address_space(1))) void*)g,
        (__attribute__((address_space(3))) void*)l, 16, 0, 0);
}

// ---------------- edges normalization ----------------
__global__ void detect_i64(const int* __restrict__ e, int* __restrict__ flag) {
    int i = blockIdx.x * 256 + threadIdx.x;
    if (i < NTRI && e[2 * i + 1] != 0) atomicOr(flag, 1);
}
__global__ void normalize_edges(const int* __restrict__ e, const int* __restrict__ flag,
                                int* __restrict__ sidx, int* __restrict__ oidx) {
    int t = blockIdx.x * 256 + threadIdx.x;
    if (t >= NTRI) return;
    bool is64 = (*flag == 0);
    int s = is64 ? e[4 * t]     : e[2 * t];
    int o = is64 ? e[4 * t + 2] : e[2 * t + 1];
    s = s < 0 ? 0 : (s >= NOBJ ? NOBJ - 1 : s);
    o = o < 0 ? 0 : (o >= NOBJ ? NOBJ - 1 : o);
    sidx[t] = s; oidx[t] = o;
}

// ---------------- f32 -> bf16 bulk convert ----------------
__global__ void to_bf16(const float* __restrict__ in, __bf16* __restrict__ out, long n4) {
    long i = (long)blockIdx.x * 256 + threadIdx.x;
    long stride = (long)gridDim.x * 256;
    for (; i < n4; i += stride) {
        float4 v = reinterpret_cast<const float4*>(in)[i];
        bf16x4 w;
        w[0] = (__bf16)v.x; w[1] = (__bf16)v.y; w[2] = (__bf16)v.z; w[3] = (__bf16)v.w;
        reinterpret_cast<bf16x4*>(out)[i] = w;
    }
}

// ---------------- weight packing ----------------
__global__ void pack_w(const float* __restrict__ W, __bf16* __restrict__ P, int K, int N) {
    int idx = blockIdx.x * 256 + threadIdx.x;
    int total = (K / 32) * (N / 16) * 64;
    if (idx >= total) return;
    int lane = idx & 63;
    int f    = idx >> 6;
    int NT   = N / 16;
    int kt = f / NT, nt = f - kt * NT;
    int krow = kt * 32 + (lane >> 4) * 8;
    int col  = nt * 16 + (lane & 15);
    __bf16 tmp[8];
#pragma unroll
    for (int i = 0; i < 8; i++) tmp[i] = (__bf16)W[(size_t)(krow + i) * N + col];
    *reinterpret_cast<bf16x8*>(P + (size_t)idx * 8) = *reinterpret_cast<const bf16x8*>(tmp);
}

// ---------------- degree counts / CSR ----------------
__global__ void count_int(const int* __restrict__ sidx, const int* __restrict__ oidx,
                          int* __restrict__ cnt) {
    int t = blockIdx.x * 256 + threadIdx.x;
    if (t >= NTRI) return;
    atomicAdd(&cnt[sidx[t]], 1);
    atomicAdd(&cnt[oidx[t]], 1);
}
__global__ void scanA(const int* __restrict__ cnt, int* __restrict__ sums) {
    __shared__ int sh[512];
    int idx = blockIdx.x * 512 + threadIdx.x;
    sh[threadIdx.x] = idx < NOBJ ? cnt[idx] : 0;
    __syncthreads();
    for (int s = 256; s > 0; s >>= 1) {
        if (threadIdx.x < s) sh[threadIdx.x] += sh[threadIdx.x + s];
        __syncthreads();
    }
    if (threadIdx.x == 0) sums[blockIdx.x] = sh[0];
}
__global__ void scanB(int* __restrict__ sums) {
    if (threadIdx.x == 0) {
        int run = 0;
        for (int i = 0; i < NSCAN; i++) { int v = sums[i]; sums[i] = run; run += v; }
    }
}
__global__ void scanC(const int* __restrict__ cnt, const int* __restrict__ sums,
                      int* __restrict__ offs, int* __restrict__ cursor) {
    __shared__ int sh[512];
    int idx = blockIdx.x * 512 + threadIdx.x;
    int v = idx < NOBJ ? cnt[idx] : 0;
    sh[threadIdx.x] = v;
    __syncthreads();
    for (int d = 1; d < 512; d <<= 1) {
        int t = (threadIdx.x >= d) ? sh[threadIdx.x - d] : 0;
        __syncthreads();
        sh[threadIdx.x] += t;
        __syncthreads();
    }
    if (idx < NOBJ) {
        int excl = sh[threadIdx.x] - v + sums[blockIdx.x];
        offs[idx] = excl; cursor[idx] = excl;
    }
}
__global__ void fill_refs(const int* __restrict__ sidx, const int* __restrict__ oidx,
                          int* __restrict__ cursor, int* __restrict__ refs) {
    int t = blockIdx.x * 256 + threadIdx.x;
    if (t >= NTRI) return;
    int p = atomicAdd(&cursor[sidx[t]], 1); refs[p] = 2 * t;
    int q = atomicAdd(&cursor[oidx[t]], 1); refs[q] = 2 * t + 1;
}

// ---------------- pooling: CSR gather mean -> x (bf16) ----------------
__global__ __launch_bounds__(512) void pool_mean(
    const __bf16* __restrict__ newso, const int* __restrict__ cnt,
    const int* __restrict__ offs, const int* __restrict__ refs,
    __bf16* __restrict__ xbuf)
{
    int w    = (blockIdx.x * 512 + threadIdx.x) >> 6;
    int lane = threadIdx.x & 63;
    if (w >= NOBJ) return;
    int n = cnt[w], off = offs[w];
    float acc[8];
#pragma unroll
    for (int i = 0; i < 8; i++) acc[i] = 0.f;
    for (int j = 0; j < n; j++) {
        int r = refs[off + j];
        const __bf16* src = newso + (size_t)(r >> 1) * 1024 + (r & 1) * 512 + lane * 8;
        bf16x8 v = *reinterpret_cast<const bf16x8*>(src);
#pragma unroll
        for (int i = 0; i < 8; i++) acc[i] += (float)v[i];
    }
    float inv = 1.f / (n > 0 ? (float)n : 1.f);
    bf16x8 o;
#pragma unroll
    for (int i = 0; i < 8; i++) o[i] = (__bf16)(acc[i] * inv);
    *reinterpret_cast<bf16x8*>(xbuf + (size_t)w * 512 + lane * 8) = o;
}

// ================= gemm1v2: h = relu(cur_t @ W1a + b1a), per 50k-chunk =================
// grid 391 x 512thr. LDS: A-full [12][128][64B] = 98304 + B dbuf 2x16KB = 131072.
// A gathered once via per-lane-source DMA; nb-loop (2 x 256 cols) stages B dbuf.
__global__ __launch_bounds__(512) void gemm1v2(
    const __bf16* __restrict__ objbf, const __bf16* __restrict__ predbf,
    const int* __restrict__ sidx, const int* __restrict__ oidx,
    const __bf16* __restrict__ pW1a, const float* __restrict__ b1a,
    __bf16* __restrict__ hbuf, int tbase)
{
    extern __shared__ char smem[];
    char* sA = smem;            // [kt][row][64B]
    char* sB = smem + 98304;    // [buf][16 frags][1024B]

    const int tid = threadIdx.x, lane = tid & 63, wid = tid >> 6;
    const int wm = wid >> 2, wn = wid & 3;
    const int r0 = blockIdx.x * 128;

    // ---- A-stage: gather cur_t (bf16) once. dest = kt*8192 + wave*1024 + lane*16 (linear) ----
    {
        int arow = tid >> 2, ac = tid & 3;
        int tloc = r0 + arow; if (tloc >= CH) tloc = CH - 1;
        int tg = tbase + tloc;
        const char* sS = (const char*)(objbf  + (size_t)sidx[tg] * DIN) + ac * 16;
        const char* sP = (const char*)(predbf + (size_t)tg       * DIN) + ac * 16;
        const char* sO = (const char*)(objbf  + (size_t)oidx[tg] * DIN) + ac * 16;
#pragma unroll
        for (int kt = 0; kt < 12; ++kt) {
            int seg = kt >> 2, cb = (kt & 3) * 64;
            const char* g = (seg == 0 ? sS : seg == 1 ? sP : sO) + cb;
            gload16(g, sA + kt * 8192 + arow * 64 + ac * 16);
        }
    }
    __syncthreads();

    for (int nb = 0; nb < 2; ++nb) {
        f32x4 acc[4][4];
#pragma unroll
        for (int mi = 0; mi < 4; mi++)
#pragma unroll
            for (int ni = 0; ni < 4; ni++) acc[mi][ni] = (f32x4){0.f, 0.f, 0.f, 0.f};

        auto stageB = [&](int buf, int kt) {
            int f0 = 2 * wid;
            const char* s0 = (const char*)pW1a + ((size_t)(kt * 32 + nb * 16 + f0)) * 1024 + lane * 16;
            gload16(s0,        sB + buf * 16384 + f0 * 1024 + lane * 16);
            gload16(s0 + 1024, sB + buf * 16384 + (f0 + 1) * 1024 + lane * 16);
        };
        stageB(0, 0);
        __syncthreads();
        int buf = 0;
        for (int kt = 0; kt < 12; ++kt) {
            if (kt + 1 < 12) stageB(buf ^ 1, kt + 1);
            bf16x8 af[4], bfr[4];
#pragma unroll
            for (int mi = 0; mi < 4; mi++) {
                int row = wm * 64 + mi * 16 + (lane & 15);
                af[mi] = *reinterpret_cast<const bf16x8*>(sA + kt * 8192 + row * 64 + (lane >> 4) * 16);
            }
#pragma unroll
            for (int ni = 0; ni < 4; ni++)
                bfr[ni] = *reinterpret_cast<const bf16x8*>(sB + buf * 16384 + (wn * 4 + ni) * 1024 + lane * 16);
#pragma unroll
            for (int ni = 0; ni < 4; ni++)
#pragma unroll
                for (int mi = 0; mi < 4; mi++)
                    acc[mi][ni] = __builtin_amdgcn_mfma_f32_16x16x32_bf16(af[mi], bfr[ni], acc[mi][ni], 0, 0, 0);
            __syncthreads();
            buf ^= 1;
        }
        // epilogue -> hbuf (chunk-local rows)
#pragma unroll
        for (int ni = 0; ni < 4; ni++) {
            int colg = nb * 256 + wn * 64 + ni * 16 + (lane & 15);
            float bv = b1a[colg];
#pragma unroll
            for (int mi = 0; mi < 4; mi++)
#pragma unroll
                for (int r = 0; r < 4; r++) {
                    int tloc = r0 + wm * 64 + mi * 16 + (lane >> 4) * 4 + r;
                    if (tloc < CH) {
                        float v = acc[mi][ni][r] + bv;
                        v = v > 0.f ? v : 0.f;
                        hbuf[(size_t)tloc * HD + colg] = (__bf16)v;
                    }
                }
        }
    }
}

// ================= gemm2v2: new_t = relu(h @ W1b + b1b), per 50k-chunk =================
// grid 391 x 512thr. LDS: A-full [16][128][64B] = 131072 + B dbuf 2x12KB = 155648.
// nb-loop: 6 chunks of 192 cols (12 frag-tiles); per-element routing in epilogue.
__global__ __launch_bounds__(512) void gemm2v2(
    const __bf16* __restrict__ hbuf,
    const __bf16* __restrict__ pW1b, const float* __restrict__ b1b,
    float* __restrict__ out_p, __bf16* __restrict__ newso, int tbase)
{
    extern __shared__ char smem[];
    char* sA = smem;             // [kt][row][64B]
    char* sB = smem + 131072;    // [buf][12 frags][1024B]

    const int tid = threadIdx.x, lane = tid & 63, wid = tid >> 6;
    const int wm = wid >> 2, wn = wid & 3;
    const int r0 = blockIdx.x * 128;

    // ---- A-stage: h rows, linear DMA ----
    {
        int arow = tid >> 2, ac = tid & 3;
        int tloc = r0 + arow; if (tloc >= CH) tloc = CH - 1;
        const char* src = (const char*)(hbuf + (size_t)tloc * HD) + ac * 16;
#pragma unroll
        for (int kt = 0; kt < 16; ++kt)
            gload16(src + kt * 64, sA + kt * 8192 + arow * 64 + ac * 16);
    }
    __syncthreads();

    for (int nb = 0; nb < 6; ++nb) {
        f32x4 acc[4][3];
#pragma unroll
        for (int mi = 0; mi < 4; mi++)
#pragma unroll
            for (int ni = 0; ni < 3; ni++) acc[mi][ni] = (f32x4){0.f, 0.f, 0.f, 0.f};

        auto stageB = [&](int buf, int kt) {
            int base = kt * 72 + nb * 12;
            const char* s0 = (const char*)pW1b + ((size_t)(base + wid)) * 1024 + lane * 16;
            gload16(s0, sB + buf * 12288 + wid * 1024 + lane * 16);
            if (wid < 4) {
                const char* s1 = (const char*)pW1b + ((size_t)(base + 8 + wid)) * 1024 + lane * 16;
                gload16(s1, sB + buf * 12288 + (8 + wid) * 1024 + lane * 16);
            }
        };
        stageB(0, 0);
        __syncthreads();
        int buf = 0;
        for (int kt = 0; kt < 16; ++kt) {
            if (kt + 1 < 16) stageB(buf ^ 1, kt + 1);
            bf16x8 af[4], bfr[3];
#pragma unroll
            for (int mi = 0; mi < 4; mi++) {
                int row = wm * 64 + mi * 16 + (lane & 15);
                af[mi] = *reinterpret_cast<const bf16x8*>(sA + kt * 8192 + row * 64 + (lane >> 4) * 16);
            }
#pragma unroll
            for (int ni = 0; ni < 3; ni++)
                bfr[ni] = *reinterpret_cast<const bf16x8*>(sB + buf * 12288 + (wn * 3 + ni) * 1024 + lane * 16);
#pragma unroll
            for (int ni = 0; ni < 3; ni++)
#pragma unroll
                for (int mi = 0; mi < 4; mi++)
                    acc[mi][ni] = __builtin_amdgcn_mfma_f32_16x16x32_bf16(af[mi], bfr[ni], acc[mi][ni], 0, 0, 0);
            __syncthreads();
            buf ^= 1;
        }
        // epilogue: route per element
#pragma unroll
        for (int ni = 0; ni < 3; ni++) {
            int colg = nb * 192 + wn * 48 + ni * 16 + (lane & 15);
            float bv = b1b[colg];
#pragma unroll
            for (int mi = 0; mi < 4; mi++)
#pragma unroll
                for (int r = 0; r < 4; r++) {
                    int tloc = r0 + wm * 64 + mi * 16 + (lane >> 4) * 4 + r;
                    if (tloc < CH) {
                        size_t tg = (size_t)(tbase + tloc);
                        float v = acc[mi][ni][r] + bv;
                        v = v > 0.f ? v : 0.f;
                        if (colg < HD)            newso[tg * 1024 + colg] = (__bf16)v;
                        else if (colg < HD + 128) out_p[tg * DOUTD + (colg - HD)] = v;
                        else                      newso[tg * 1024 + 512 + (colg - 640)] = (__bf16)v;
                    }
                }
        }
    }
}

// ---------------- fused GEMM3 + GEMM4 (aliased LDS) ----------------
__global__ __launch_bounds__(512, 4) void fused34(
    const __bf16* __restrict__ xbuf,
    const __bf16* __restrict__ pW2a, const float* __restrict__ b2a,
    const __bf16* __restrict__ pW2b, const float* __restrict__ b2b,
    float* __restrict__ out_obj)
{
    extern __shared__ char smem[];
    __bf16* sX = (__bf16*)smem;

    const int tid  = threadIdx.x;
    const int lane = tid & 63;
    const int wid  = tid >> 6;
    const int o0   = blockIdx.x * 64;

    for (int u = tid; u < 64 * 64; u += 512) {
        int part = u & 63;
        int row  = u >> 6;
        int ob   = o0 + row;
        bf16x8 v;
        if (ob < NOBJ) v = *reinterpret_cast<const bf16x8*>(xbuf + (size_t)ob * 512 + part * 8);
        else { bf16x8 z = {}; v = z; }
        *reinterpret_cast<bf16x8*>(sX + row * SB_STRIDE + part * 8) = v;
    }
    __syncthreads();

    const int wm = wid >> 2;
    const int wn = wid & 3;
    const int lk = (lane >> 4) * 8;
    const int lr = lane & 15;
    const int rbase = (lane >> 4) * 4;

    {
        f32x4 acc[2][8];
#pragma unroll
        for (int mi = 0; mi < 2; mi++)
#pragma unroll
            for (int ni = 0; ni < 8; ni++) acc[mi][ni] = (f32x4){0.f, 0.f, 0.f, 0.f};

        for (int kt = 0; kt < HD / 32; ++kt) {
            bf16x8 a0 = *reinterpret_cast<const bf16x8*>(sX + (wm * 32 + lr) * SB_STRIDE + kt * 32 + lk);
            bf16x8 a1 = *reinterpret_cast<const bf16x8*>(sX + (wm * 32 + 16 + lr) * SB_STRIDE + kt * 32 + lk);
#pragma unroll
            for (int ni = 0; ni < 8; ni++) {
                bf16x8 b = *reinterpret_cast<const bf16x8*>(pW2a + (((size_t)(kt * 32 + wn * 8 + ni)) * 64 + lane) * 8);
                acc[0][ni] = __builtin_amdgcn_mfma_f32_16x16x32_bf16(a0, b, acc[0][ni], 0, 0, 0);
                acc[1][ni] = __builtin_amdgcn_mfma_f32_16x16x32_bf16(a1, b, acc[1][ni], 0, 0, 0);
            }
        }
        __syncthreads();

#pragma unroll
        for (int mi = 0; mi < 2; mi++)
#pragma unroll
            for (int ni = 0; ni < 8; ni++) {
                int col = wn * 128 + ni * 16 + lr;
                float bv = b2a[col];
#pragma unroll
                for (int r = 0; r < 4; r++) {
                    float v = acc[mi][ni][r] + bv;
                    v = v > 0.f ? v : 0.f;
                    sX[(wm * 32 + mi * 16 + rbase + r) * SB_STRIDE + col] = (__bf16)v;
                }
            }
    }
    __syncthreads();

    {
        f32x4 acc[2][2];
#pragma unroll
        for (int mi = 0; mi < 2; mi++)
#pragma unroll
            for (int ni = 0; ni < 2; ni++) acc[mi][ni] = (f32x4){0.f, 0.f, 0.f, 0.f};

        for (int kt = 0; kt < HD / 32; ++kt) {
            bf16x8 a0 = *reinterpret_cast<const bf16x8*>(sX + (wm * 32 + lr) * SB_STRIDE + kt * 32 + lk);
            bf16x8 a1 = *reinterpret_cast<const bf16x8*>(sX + (wm * 32 + 16 + lr) * SB_STRIDE + kt * 32 + lk);
#pragma unroll
            for (int ni = 0; ni < 2; ni++) {
                int f = kt * 8 + wn * 2 + ni;
                bf16x8 b = *reinterpret_cast<const bf16x8*>(pW2b + ((size_t)f * 64 + lane) * 8);
                acc[0][ni] = __builtin_amdgcn_mfma_f32_16x16x32_bf16(a0, b, acc[0][ni], 0, 0, 0);
                acc[1][ni] = __builtin_amdgcn_mfma_f32_16x16x32_bf16(a1, b, acc[1][ni], 0, 0, 0);
            }
        }
#pragma unroll
        for (int mi = 0; mi < 2; mi++)
#pragma unroll
            for (int ni = 0; ni < 2; ni++) {
                int col = wn * 32 + ni * 16 + lr;
                float bv = b2b[col];
#pragma unroll
                for (int r = 0; r < 4; r++) {
                    int row = wm * 32 + mi * 16 + rbase + r;
                    int ob  = o0 + row;
                    if (ob < NOBJ) {
                        float v = acc[mi][ni][r] + bv;
                        v = v > 0.f ? v : 0.f;
                        out_obj[(size_t)ob * DOUTD + col] = v;
                    }
                }
            }
    }
}

// ---------------- launch ----------------
extern "C" void kernel_launch(void* const* d_in, const int* in_sizes, int n_in,
                              void* d_out, int out_size, void* d_ws, size_t ws_size,
                              hipStream_t stream)
{
    const float* obj   = (const float*)d_in[0];
    const float* pred  = (const float*)d_in[1];
    const int*   edges = (const int*)d_in[2];
    const float* W1a = (const float*)d_in[3];
    const float* b1a = (const float*)d_in[4];
    const float* W1b = (const float*)d_in[5];
    const float* b1b = (const float*)d_in[6];
    const float* W2a = (const float*)d_in[7];
    const float* b2a = (const float*)d_in[8];
    const float* W2b = (const float*)d_in[9];
    const float* b2b = (const float*)d_in[10];

    float* out_obj = (float*)d_out;
    float* out_p   = (float*)d_out + (size_t)NOBJ * DOUTD;

    // ws layout (all within PROVEN 467,028,928 bytes):
    // [0) sidx  [800000) oidx  [1800000) flag  [1800064) packed W (ends 4,028,288)
    // [4028416) cnt  [4228416) offs  [4428416) cursor  [4628416) sums  [4628928) refs
    // [6228928) hbuf/xbuf (51.2MB, time-shared)  [57428928) newso (409.6MB, ends 467,028,928)
    // Overlays inside newso tail (triples >= 168,750, written only by gemm2 chunk 3, last):
    //   predbf @403,028,928 (51.2MB)   objbf @454,228,928 (12.8MB)
    char* ws = (char*)d_ws;
    int*    sidx   = (int*)ws;
    int*    oidx   = sidx + NTRI;
    int*    flag   = (int*)(ws + 1800000);
    __bf16* pW1a   = (__bf16*)(ws + 1800064);
    __bf16* pW1b   = pW1a + 196608;
    __bf16* pW2a   = pW1b + 589824;
    __bf16* pW2b   = pW2a + 262144;
    int*    cnt    = (int*)(ws + 4028416);
    int*    offs   = (int*)(ws + 4228416);
    int*    cursor = (int*)(ws + 4428416);
    int*    sums   = (int*)(ws + 4628416);
    int*    refs   = (int*)(ws + 4628928);
    __bf16* hbuf   = (__bf16*)(ws + 6228928);      // also xbuf (after GEMMs done)
    __bf16* xbuf   = hbuf;
    __bf16* newso  = (__bf16*)(ws + 57428928);
    __bf16* predbf = (__bf16*)(ws + 403028928);
    __bf16* objbf  = (__bf16*)(ws + 454228928);

    hipMemsetAsync(flag, 0, 4, stream);
    detect_i64<<<(NTRI + 255) / 256, 256, 0, stream>>>(edges, flag);
    normalize_edges<<<(NTRI + 255) / 256, 256, 0, stream>>>(edges, flag, sidx, oidx);

    pack_w<<<(24576 + 255) / 256, 256, 0, stream>>>(W1a, pW1a, 384, 512);
    pack_w<<<(73728 + 255) / 256, 256, 0, stream>>>(W1b, pW1b, 512, 1152);
    pack_w<<<(32768 + 255) / 256, 256, 0, stream>>>(W2a, pW2a, 512, 512);
    pack_w<<<(8192  + 255) / 256, 256, 0, stream>>>(W2b, pW2b, 512, 128);

    hipMemsetAsync(cnt, 0, 200000, stream);
    count_int<<<(NTRI + 255) / 256, 256, 0, stream>>>(sidx, oidx, cnt);
    scanA<<<NSCAN, 512, 0, stream>>>(cnt, sums);
    scanB<<<1, 64, 0, stream>>>(sums);
    scanC<<<NSCAN, 512, 0, stream>>>(cnt, sums, offs, cursor);
    fill_refs<<<(NTRI + 255) / 256, 256, 0, stream>>>(sidx, oidx, cursor, refs);

    to_bf16<<<2048, 256, 0, stream>>>(obj,  objbf,  (long)NOBJ * DIN / 4);
    to_bf16<<<2048, 256, 0, stream>>>(pred, predbf, (long)NTRI * DIN / 4);

    const size_t lds1 = 131072;   // 98304 A + 32768 B-dbuf
    const size_t lds2 = 155648;   // 131072 A + 24576 B-dbuf
    const int    gblk = (CH + 127) / 128;   // 391
    for (int c = 0; c < 4; ++c) {
        gemm1v2<<<gblk, 512, lds1, stream>>>(objbf, predbf, sidx, oidx, pW1a, b1a, hbuf, c * CH);
        gemm2v2<<<gblk, 512, lds2, stream>>>(hbuf, pW1b, b1b, out_p, newso, c * CH);
    }

    pool_mean<<<(NOBJ * 64 + 511) / 512, 512, 0, stream>>>(newso, cnt, offs, refs, xbuf);
    size_t lds34 = (size_t)64 * SB_STRIDE * 2;
    fused34<<<(NOBJ + 63) / 64, 512, lds34, stream>>>(xbuf, pW2a, b2a, pW2b, b2b, out_obj);
}